// Round 11
// baseline (324.925 us; speedup 1.0000x reference)
//
#include <hip/hip_runtime.h>
#include <stdint.h>

constexpr int B = 8, N = 8192, S = 2048, D1 = 128, D2 = 256;
constexpr int CIN = 384, CMID = 256, COUT = 256;

typedef __attribute__((ext_vector_type(8))) _Float16 half8;
typedef __attribute__((ext_vector_type(4))) _Float16 half4;
typedef __attribute__((ext_vector_type(4))) float f32x4;

union HU { uint32_t u; _Float16 h[2]; };

// d_out layout during the pipeline (float index (b*256+r)*8192+n):
//   rows   0..127 : hA2 (after k_interp) then h2 (after k_h) — fp16 x2 packed
//   rows 128..191 : (1) k_top3a/b candidate scratch: per b, 24 d-planes at
//                   cd[(sp*3+k)*N+n], 24 idx-planes at cd+196608; dead after
//                   k_top3b. (2) then Gt_b (k_G), fp32 [s][o]
//   rows 192..207 : k_h per-block BN partial sums
// k_fused1 finally overwrites ALL of d_out with fp32 output.

// -------------------------------------------- top-3 NN, stage a: per-s-split
// T=2 n/lane WITH R8's 2-round grid (the one untested combination):
// grid (N/128, B, 8) = 4096 blocks (= R8's count -> same 2-rounds-of-8/CU
// pipelining), 256-s chunk in 4 KB LDS, 13.3 KB total. One broadcast
// ds_read_b128 feeds 2 independent n-chains (halves the 41 µs LDS-pipe cost
// measured at R8; R9's T=2 null was confounded by its 1-round grid).
// Rank key d' = |s|^2 - 2<a,s> (|a|^2 re-added in stage b).
__global__ __launch_bounds__(256) void k_top3a(const float* __restrict__ xyz1,
                                               const float* __restrict__ xyz2,
                                               float* __restrict__ dout) {
  __shared__ float4 Pq[256];               // 4 KB
  __shared__ float md[4][3][128];          // 6 KB
  __shared__ unsigned short mi[4][3][128]; // 3 KB (s < 2048 fits u16)
  const int tid = threadIdx.x;
  const int wv = tid >> 6, lane = tid & 63;
  const int b = blockIdx.y;
  const int sp = blockIdx.z;          // s-split 0..7
  const int sbase = sp * 256;
  const int nb = blockIdx.x * 128;    // block's base n (128 n per block)
  const float* x1 = xyz1 + (size_t)b * 3 * N;
  const float* x2 = xyz2 + (size_t)b * 3 * S;

  {
    const int s = sbase + tid;        // 256 threads cover the 256-s chunk
    float sx = x2[s], sy = x2[s + S], sz = x2[s + 2 * S];
    Pq[tid] = float4{sx, sy, sz, sx * sx + sy * sy + sz * sz};
  }
  float nax[2], nay[2], naz[2];
#pragma unroll
  for (int t = 0; t < 2; ++t) {
    const int n = nb + t * 64 + lane;
    const float ax = x1[n], ay = x1[n + N], az = x1[n + 2 * N];
    nax[t] = -2.f * ax; nay[t] = -2.f * ay; naz[t] = -2.f * az;
  }
  __syncthreads();

  float e0[2], e1[2], e2[2];
  int j0[2], j1[2], j2[2];
#pragma unroll
  for (int t = 0; t < 2; ++t) {
    e0[t] = 1e30f; e1[t] = 1e30f; e2[t] = 1e30f;
    j0[t] = 0; j1[t] = 0; j2[t] = 0;
  }
  const int q0 = wv * 64, q1 = q0 + 64;   // wave's 64-s sub-range (ascending)
#pragma unroll 4
  for (int j = q0; j < q1; ++j) {
    const float4 v = Pq[j];
    const int s = sbase + j;
#pragma unroll
    for (int t = 0; t < 2; ++t) {
      const float d = fmaf(nax[t], v.x, fmaf(nay[t], v.y, fmaf(naz[t], v.z, v.w)));
      // strict < : stable (lowest index wins ties)
      const bool c0 = d < e0[t], c1 = d < e1[t], c2 = d < e2[t];
      const int u2 = c1 ? j1[t] : s;
      const int u1 = c0 ? j0[t] : s;
      j2[t] = c2 ? u2 : j2[t];
      j1[t] = c1 ? u1 : j1[t];
      j0[t] = c0 ? s : j0[t];
      // e0<=e1<=e2 invariant: sorted-insert via 2 med3 + 1 min
      e2[t] = __builtin_amdgcn_fmed3f(e1[t], e2[t], d);
      e1[t] = __builtin_amdgcn_fmed3f(e0[t], e1[t], d);
      e0[t] = fminf(e0[t], d);
    }
  }
#pragma unroll
  for (int t = 0; t < 2; ++t) {
    const int idx = t * 64 + lane;
    md[wv][0][idx] = e0[t]; mi[wv][0][idx] = (unsigned short)j0[t];
    md[wv][1][idx] = e1[t]; mi[wv][1][idx] = (unsigned short)j1[t];
    md[wv][2][idx] = e2[t]; mi[wv][2][idx] = (unsigned short)j2[t];
  }
  __syncthreads();
  if (tid < 128) {
    // each thread merges one n (= nb + tid) across the 4 waves' partials
    float f0 = md[0][0][tid], f1 = md[0][1][tid], f2 = md[0][2][tid];
    int g0 = mi[0][0][tid], g1 = mi[0][1][tid], g2 = mi[0][2][tid];
#pragma unroll
    for (int w = 1; w < 4; ++w)
#pragma unroll
      for (int k = 0; k < 3; ++k) {
        float d = md[w][k][tid];
        int i = mi[w][k][tid];
        if (d < f2) {  // ascending-s wave order + strict < = stable ties
          if (d < f1) {
            f2 = f1; g2 = g1;
            if (d < f0) { f1 = f0; g1 = g0; f0 = d; g0 = i; }
            else        { f1 = d;  g1 = i; }
          } else { f2 = d; g2 = i; }
        }
      }
    // write 3 candidates (rank key d', idx) to scratch planes
    const int nm = nb + tid;
    float* cd = dout + ((size_t)(b * 256 + 128)) * 8192;
    uint32_t* ci = (uint32_t*)cd + 196608;   // 24*8192 floats after d-planes
    cd[(sp * 3 + 0) * N + nm] = f0; ci[(sp * 3 + 0) * N + nm] = (uint32_t)g0;
    cd[(sp * 3 + 1) * N + nm] = f1; ci[(sp * 3 + 1) * N + nm] = (uint32_t)g1;
    cd[(sp * 3 + 2) * N + nm] = f2; ci[(sp * 3 + 2) * N + nm] = (uint32_t)g2;
  }
}

// -------------------------------------------- top-3 NN, stage b: merge+pack
// One thread per n: fold 8 splits × 3 candidates (ascending split = ascending
// s-range -> strict < keeps lowest-index ties), add |x1|^2, weights, pack.
__global__ __launch_bounds__(256) void k_top3b(const float* __restrict__ xyz1,
                                               const float* __restrict__ dout,
                                               uint32_t* __restrict__ pw3) {
  const int gid = blockIdx.x * 256 + threadIdx.x;  // B*N
  const int b = gid >> 13, n = gid & 8191;
  const float* cd = dout + ((size_t)(b * 256 + 128)) * 8192;
  const uint32_t* ci = (const uint32_t*)cd + 196608;
  float f0 = 1e30f, f1 = 1e30f, f2 = 1e30f;
  int g0 = 0, g1 = 0, g2 = 0;
#pragma unroll
  for (int t = 0; t < 24; ++t) {
    float d = cd[(size_t)t * N + n];
    int i = (int)ci[(size_t)t * N + n];
    if (d < f2) {
      if (d < f1) {
        f2 = f1; g2 = g1;
        if (d < f0) { f1 = f0; g1 = g0; f0 = d; g0 = i; }
        else        { f1 = d;  g1 = i; }
      } else { f2 = d; g2 = i; }
    }
  }
  const float* x1 = xyz1 + (size_t)b * 3 * N;
  const float ax = x1[n], ay = x1[n + N], az = x1[n + 2 * N];
  const float rn = ax * ax + ay * ay + az * az;
  // recover true squared distances (clamp: fp rounding can go slightly neg)
  float q0 = fmaxf(f0 + rn, 0.f);
  float q1 = fmaxf(f1 + rn, 0.f);
  float q2 = fmaxf(f2 + rn, 0.f);
  float r0 = 1.0f / (q0 + 1e-8f), r1 = 1.0f / (q1 + 1e-8f), r2 = 1.0f / (q2 + 1e-8f);
  float inv = 1.0f / (r0 + r1 + r2);
  auto pack = [](int i, float w) -> uint32_t {
    uint32_t q = (uint32_t)(w * 2097152.0f + 0.5f);
    if (q > 0x1FFFFFu) q = 0x1FFFFFu;
    return ((uint32_t)i << 21) | q;
  };
  size_t base = ((size_t)b * N + n) * 3;
  pw3[base]     = pack(g0, r0 * inv);
  pw3[base + 1] = pack(g1, r1 * inv);
  pw3[base + 2] = pack(g2, r2 * inv);
}

// ---------------------------- k_G: Gt_b[s][o] = (W0[:,0:256] @ points2_b)^T
__global__ __launch_bounds__(256) void k_G(const float* __restrict__ points2,
                                           const float* __restrict__ W0,
                                           float* __restrict__ dout) {
  __shared__ half8 A_lds[4][256];
  __shared__ half8 B_lds[4][32];
  __shared__ float CT[32][258];
  const int tid = threadIdx.x;
  const int b = blockIdx.x >> 6;
  const int s0 = (blockIdx.x & 63) * 32;
  f32x4 acc[4][2] = {};
  const int wv = tid >> 6, lane = tid & 63;
  const int ln = lane & 15, quad = lane >> 4;
  const int bn = tid & 31, bkc = tid >> 5;
  const int ar = tid >> 3, ac4 = tid & 7;

  for (int kk = 0; kk < 256; kk += 32) {
    __syncthreads();
#pragma unroll
    for (int p = 0; p < 8; ++p) {
      int row = ar + 32 * p;
      const float4 v = *(const float4*)(W0 + (size_t)row * CIN + kk + ac4 * 4);
      half4 hv = {(_Float16)v.x, (_Float16)v.y, (_Float16)v.z, (_Float16)v.w};
      *(half4*)((_Float16*)&A_lds[ac4 >> 1][row] + (ac4 & 1) * 4) = hv;
    }
    {
      half4 hv;
#pragma unroll
      for (int j = 0; j < 4; ++j)
        hv[j] = (_Float16)points2[((size_t)(b * 256 + kk + bkc * 4 + j)) * S + s0 + bn];
      *(half4*)((_Float16*)&B_lds[bkc >> 1][bn] + (bkc & 1) * 4) = hv;
    }
    __syncthreads();
    half8 af[4], bf[2];
#pragma unroll
    for (int i = 0; i < 4; ++i) af[i] = A_lds[quad][wv * 64 + i * 16 + ln];
#pragma unroll
    for (int j = 0; j < 2; ++j) bf[j] = B_lds[quad][j * 16 + ln];
#pragma unroll
    for (int i = 0; i < 4; ++i)
#pragma unroll
      for (int j = 0; j < 2; ++j)
        acc[i][j] = __builtin_amdgcn_mfma_f32_16x16x32_f16(af[i], bf[j], acc[i][j], 0, 0, 0);
  }
  __syncthreads();
#pragma unroll
  for (int i = 0; i < 4; ++i)
#pragma unroll
    for (int reg = 0; reg < 4; ++reg) {
      int row = wv * 64 + i * 16 + quad * 4 + reg;
#pragma unroll
      for (int j = 0; j < 2; ++j) CT[j * 16 + ln][row] = acc[i][j][reg];
    }
  __syncthreads();
  const int sl = tid >> 3, g = tid & 7;
  float* g0 = dout + ((size_t)(b * 256 + 128)) * 8192 + (size_t)(s0 + sl) * 256 + g * 32;
#pragma unroll
  for (int q = 0; q < 8; ++q)
    *(float4*)(g0 + q * 4) = *(const float4*)&CT[sl][g * 32 + q * 4];
}

// --------------- k_interp: hA2[b][cp][n] = pack(sum_k w_k * Gt_b[j_k][2cp..])
__global__ __launch_bounds__(256) void k_interp(const uint32_t* __restrict__ pw3,
                                                const float* __restrict__ dout_c,
                                                uint32_t* __restrict__ dout_u) {
  __shared__ int sidx[96];
  __shared__ float sw[96];
  const int tid = threadIdx.x;
  const int b = blockIdx.x >> 8;
  const int n0 = (blockIdx.x & 255) * 32;
  if (tid < 96) {
    uint32_t p = pw3[((size_t)b * N + n0) * 3 + tid];
    sidx[tid] = (int)(p >> 21);
    sw[tid] = (float)(p & 0x1FFFFFu) * (1.0f / 2097152.0f);
  }
  __syncthreads();
  const int colL = tid >> 3, p = tid & 7;  // 8 lanes/col, 32 channels each
  const float* Gb = dout_c + ((size_t)(b * 256 + 128)) * 8192;
  float a[32];
#pragma unroll
  for (int q = 0; q < 32; ++q) a[q] = 0.f;
#pragma unroll
  for (int k = 0; k < 3; ++k) {
    int j = sidx[colL * 3 + k];
    float w = sw[colL * 3 + k];
    const float* g = Gb + (size_t)j * 256 + p * 32;
#pragma unroll
    for (int q = 0; q < 8; ++q) {
      float4 v = *(const float4*)(g + q * 4);
      a[q * 4 + 0] += w * v.x; a[q * 4 + 1] += w * v.y;
      a[q * 4 + 2] += w * v.z; a[q * 4 + 3] += w * v.w;
    }
  }
#pragma unroll
  for (int q = 0; q < 16; ++q) {
    int cp = p * 16 + q;
    HU u;
    u.h[0] = (_Float16)a[2 * q];
    u.h[1] = (_Float16)a[2 * q + 1];
    dout_u[((size_t)(b * 256 + cp)) * 8192 + n0 + colL] = u.u;
  }
}

// --------- k_wpack: pre-pack W1 (fp32 [256][256]) -> fp16 [256][256]  AND
// W0[:,256:384] (fp32, ld=384) -> fp16 [256][128]. Lands in the ws region
// previously used by pw3 (dead after k_interp).
__global__ __launch_bounds__(256) void k_wpack(const float* __restrict__ W0,
                                               const float* __restrict__ W1,
                                               _Float16* __restrict__ W1h,
                                               _Float16* __restrict__ W0h) {
  const int bid = blockIdx.x;
  if (bid < 64) {
    const int gid = bid * 256 + threadIdx.x;  // 16384 float4s
    const float4 v = *(const float4*)(W1 + (size_t)gid * 4);
    half4 h = {(_Float16)v.x, (_Float16)v.y, (_Float16)v.z, (_Float16)v.w};
    *(half4*)(W1h + (size_t)gid * 4) = h;
  } else {
    const int gid = (bid - 64) * 256 + threadIdx.x;  // 8192 float4s
    const int row = gid >> 5, c4 = gid & 31;         // 32 float4 per row
    const float4 v = *(const float4*)(W0 + (size_t)row * CIN + 256 + c4 * 4);
    half4 h = {(_Float16)v.x, (_Float16)v.y, (_Float16)v.z, (_Float16)v.w};
    *(half4*)(W0h + (size_t)row * 128 + c4 * 4) = h;
  }
}

// ------- k_h: h = hA + W0[:,256:384]@p1 + b0; write packed fp16 h2 in place
// over hA2; emit per-block BN partials into d_out rows 192..207.
__global__ __launch_bounds__(256) void k_h(uint32_t* __restrict__ h2,
                                           float* __restrict__ dpart,
                                           const float* __restrict__ points1,
                                           const _Float16* __restrict__ W0h,
                                           const float* __restrict__ b0) {
  __shared__ half8 B_lds[16][32];   // 8 KB: [K-chunk(8K)][col]
  __shared__ float red_s[256], red_q[256], sb0[256];
  const int tid = threadIdx.x;
  const int b = blockIdx.x >> 8;
  const int cb = blockIdx.x & 255;
  const int n0 = cb * 32;
  sb0[tid] = b0[tid];
  const int wv = tid >> 6, lane = tid & 63;
  const int ln = lane & 15, quad = lane >> 4;

  // ---- init acc = hA (C-in); loads issue first, waited at first MFMA
  f32x4 acc[4][2];
#pragma unroll
  for (int i = 0; i < 4; ++i) {
    const int rb = wv * 64 + i * 16 + quad * 4;
    const int cp0 = rb >> 1;
#pragma unroll
    for (int j = 0; j < 2; ++j) {
      const int col = n0 + j * 16 + ln;
      const size_t a0 = ((size_t)(b * 256 + cp0)) * 8192 + col;
      HU ua, ub;
      ua.u = h2[a0];
      ub.u = h2[a0 + 8192];
      acc[i][j][0] = (float)ua.h[0];
      acc[i][j][1] = (float)ua.h[1];
      acc[i][j][2] = (float)ub.h[0];
      acc[i][j][3] = (float)ub.h[1];
    }
  }
  // ---- stage points1 [128K][32cols] -> fp16 LDS (one barrier total)
  {
    const int col = tid & 31;
    const int kc0 = tid >> 5;           // 0..7
#pragma unroll
    for (int it = 0; it < 2; ++it) {
      const int kc = kc0 + 8 * it;      // 0..15
      half8 hv;
#pragma unroll
      for (int j = 0; j < 8; ++j)
        hv[j] = (_Float16)points1[((size_t)(b * D1 + kc * 8 + j)) * N + n0 + col];
      B_lds[kc][col] = hv;
    }
  }
  __syncthreads();
  // ---- sync-free K-loop, af straight from global W0h
  for (int kk = 0; kk < 128; kk += 32) {
    half8 af[4], bf[2];
#pragma unroll
    for (int i = 0; i < 4; ++i) {
      const int row = wv * 64 + i * 16 + ln;
      af[i] = *(const half8*)(W0h + (size_t)row * 128 + kk + quad * 8);
    }
#pragma unroll
    for (int j = 0; j < 2; ++j)
      bf[j] = B_lds[(kk >> 3) + quad][j * 16 + ln];
#pragma unroll
    for (int i = 0; i < 4; ++i)
#pragma unroll
      for (int j = 0; j < 2; ++j)
        acc[i][j] = __builtin_amdgcn_mfma_f32_16x16x32_f16(af[i], bf[j], acc[i][j], 0, 0, 0);
  }
  // ---- epilogue: +b0, round fp16, store in place, accumulate row sums
#pragma unroll
  for (int i = 0; i < 4; ++i) {
    const int rb = wv * 64 + i * 16 + quad * 4;
    const int cp0 = rb >> 1;
    float rs[4] = {0.f, 0.f, 0.f, 0.f}, rq[4] = {0.f, 0.f, 0.f, 0.f};
#pragma unroll
    for (int j = 0; j < 2; ++j) {
      const int col = n0 + j * 16 + ln;
      const size_t a0 = ((size_t)(b * 256 + cp0)) * 8192 + col;
      _Float16 e0 = (_Float16)(acc[i][j][0] + sb0[rb + 0]);
      _Float16 e1 = (_Float16)(acc[i][j][1] + sb0[rb + 1]);
      _Float16 e2 = (_Float16)(acc[i][j][2] + sb0[rb + 2]);
      _Float16 e3 = (_Float16)(acc[i][j][3] + sb0[rb + 3]);
      HU o0, o1;
      o0.h[0] = e0; o0.h[1] = e1; o1.h[0] = e2; o1.h[1] = e3;
      h2[a0] = o0.u;
      h2[a0 + 8192] = o1.u;
      float f0 = (float)e0, f1 = (float)e1, f2 = (float)e2, f3 = (float)e3;
      rs[0] += f0; rq[0] += f0 * f0;
      rs[1] += f1; rq[1] += f1 * f1;
      rs[2] += f2; rq[2] += f2 * f2;
      rs[3] += f3; rq[3] += f3 * f3;
    }
#pragma unroll
    for (int reg = 0; reg < 4; ++reg) {
      float s = rs[reg], q = rq[reg];
#pragma unroll
      for (int m = 1; m < 16; m <<= 1) {
        s += __shfl_xor(s, m);
        q += __shfl_xor(q, m);
      }
      if (ln == 0) { red_s[rb + reg] = s; red_q[rb + reg] = q; }
    }
  }
  __syncthreads();
  float* part = dpart + ((size_t)(b * 256 + 192)) * 8192 + (size_t)cb * 512;
  part[tid] = red_s[tid];
  part[256 + tid] = red_q[tid];
}

// ------------------------- k_bn: reduce 2048 partials/channel -> a,b per chan
__global__ __launch_bounds__(256) void k_bn(const float* __restrict__ dpart,
                                            const float* __restrict__ gamma,
                                            const float* __restrict__ beta,
                                            float* __restrict__ bna,
                                            float* __restrict__ bnb) {
  const int c = blockIdx.x;
  const int tid = threadIdx.x;
  float s = 0.f, q = 0.f;
#pragma unroll
  for (int u = tid; u < 2048; u += 256) {
    int b = u >> 8, cb = u & 255;
    const float* part = dpart + ((size_t)(b * 256 + 192)) * 8192 + (size_t)cb * 512;
    s += part[c];
    q += part[256 + c];
  }
#pragma unroll
  for (int m = 1; m < 64; m <<= 1) {
    s += __shfl_xor(s, m);
    q += __shfl_xor(q, m);
  }
  __shared__ float ls[4], lq[4];
  if ((tid & 63) == 0) { ls[tid >> 6] = s; lq[tid >> 6] = q; }
  __syncthreads();
  if (tid == 0) {
    float st = ls[0] + ls[1] + ls[2] + ls[3];
    float qt = lq[0] + lq[1] + lq[2] + lq[3];
    const float invn = 1.0f / (float)(B * N);
    float mean = st * invn;
    float var = qt * invn - mean * mean;  // biased, matches reference
    float a = gamma[c] * rsqrtf(var + 1e-5f);
    bna[c] = a;
    bnb[c] = beta[c] - mean * a;
  }
}

// ------- k_fused1: out = relu(W1 @ relu(a*h+b) + b1), fp32 over all of d_out.
__global__ __launch_bounds__(256) void k_fused1(const uint32_t* h2,
                                                const _Float16* __restrict__ W1h,
                                                const float* __restrict__ b1,
                                                const float* __restrict__ bna,
                                                const float* __restrict__ bnb,
                                                float* out) {
  __shared__ uint32_t Hh[32 * 33 * 4];  // [kc][col(+1 pad)][k&7] halfs, 16.9 KB
  __shared__ float sa[256], sb[256], sb1[256];
  const int tid = threadIdx.x;
  const int b = blockIdx.x >> 8;
  const int n0 = (blockIdx.x & 255) * 32;
  sa[tid] = bna[tid]; sb[tid] = bnb[tid]; sb1[tid] = b1[tid];
  __syncthreads();
  {
    // 128 packed rows x 32 cols; each thread: 4 x uint4 (4 cols x 4 cps)
    const int c4 = tid & 7;          // col group: cols c4*4 .. c4*4+3
    const int rg = tid >> 3;         // 0..31
#pragma unroll
    for (int q = 0; q < 4; ++q) {
      const int cp = rg + 32 * q;    // 0..127
      const uint4 v = *(const uint4*)&h2[((size_t)(b * 256 + cp)) * 8192 + n0 + c4 * 4];
      const int k0 = 2 * cp;
      const float a0 = sa[k0], a1 = sa[k0 + 1], b0v = sb[k0], b1v = sb[k0 + 1];
      const int kc = cp >> 2, sub = cp & 3;
      const uint32_t vv[4] = {v.x, v.y, v.z, v.w};
#pragma unroll
      for (int m = 0; m < 4; ++m) {
        HU u; u.u = vv[m];
        float v0 = a0 * (float)u.h[0] + b0v;
        float v1 = a1 * (float)u.h[1] + b1v;
        HU o;
        o.h[0] = (_Float16)(v0 > 0.f ? v0 : 0.f);
        o.h[1] = (_Float16)(v1 > 0.f ? v1 : 0.f);
        Hh[((kc * 33) + c4 * 4 + m) * 4 + sub] = o.u;
      }
    }
  }
  __syncthreads();
  f32x4 acc[4][2] = {};
  const int wv = tid >> 6, lane = tid & 63;
  const int ln = lane & 15, quad = lane >> 4;
  for (int kk = 0; kk < 256; kk += 32) {
    half8 af[4], bf[2];
#pragma unroll
    for (int i = 0; i < 4; ++i) {
      int row = wv * 64 + i * 16 + ln;
      af[i] = *(const half8*)(W1h + (size_t)row * CMID + kk + quad * 8);
    }
#pragma unroll
    for (int j = 0; j < 2; ++j)
      bf[j] = *(const half8*)&Hh[(((kk >> 3) + quad) * 33 + j * 16 + ln) * 4];
#pragma unroll
    for (int i = 0; i < 4; ++i)
#pragma unroll
      for (int j = 0; j < 2; ++j)
        acc[i][j] = __builtin_amdgcn_mfma_f32_16x16x32_f16(af[i], bf[j], acc[i][j], 0, 0, 0);
  }
#pragma unroll
  for (int i = 0; i < 4; ++i) {
    const int rb = wv * 64 + i * 16 + quad * 4;
#pragma unroll
    for (int reg = 0; reg < 4; ++reg) {
      int row = rb + reg;
      float bias = sb1[row];
      float* orow = out + ((size_t)(b * 256 + row)) * 8192 + n0;
#pragma unroll
      for (int j = 0; j < 2; ++j)
        orow[j * 16 + ln] = fmaxf(acc[i][j][reg] + bias, 0.f);
    }
  }
}

extern "C" void kernel_launch(void* const* d_in, const int* in_sizes, int n_in,
                              void* d_out, int out_size, void* d_ws, size_t ws_size,
                              hipStream_t stream) {
  const float* xyz1 = (const float*)d_in[0];
  const float* xyz2 = (const float*)d_in[1];
  const float* points1 = (const float*)d_in[2];
  const float* points2 = (const float*)d_in[3];
  const float* W0 = (const float*)d_in[4];
  const float* b0 = (const float*)d_in[5];
  const float* gamma0 = (const float*)d_in[6];
  const float* beta0 = (const float*)d_in[7];
  const float* W1 = (const float*)d_in[8];
  const float* b1 = (const float*)d_in[9];
  float* out = (float*)d_out;

  // ws layout (788,480 B == R1's proven-safe size; do NOT grow):
  //   [0,1K) bna | [1K,2K) bnb | [2K,770K) pw3
  // After k_interp, pw3 is dead -> region reused: W1h (128 KB) + W0h (64 KB).
  char* ws = (char*)d_ws;
  float* bna = (float*)ws;
  float* bnb = (float*)(ws + 1024);
  uint32_t* pw3 = (uint32_t*)(ws + 2048);
  _Float16* W1h = (_Float16*)(ws + 2048);            // overlays pw3
  _Float16* W0h = (_Float16*)(ws + 2048 + 131072);   // after W1h

  k_top3a<<<dim3(N / 128, B, 8), 256, 0, stream>>>(xyz1, xyz2, out);
  k_top3b<<<dim3(B * N / 256), 256, 0, stream>>>(xyz1, out, pw3);
  k_G<<<dim3(B * 64), 256, 0, stream>>>(points2, W0, out);
  k_interp<<<dim3(B * N / 32), 256, 0, stream>>>(pw3, out, (uint32_t*)out);
  k_wpack<<<dim3(96), 256, 0, stream>>>(W0, W1, W1h, W0h);
  k_h<<<dim3(B * N / 32), 256, 0, stream>>>((uint32_t*)out, out, points1, W0h, b0);
  k_bn<<<dim3(256), 256, 0, stream>>>(out, gamma0, beta0, bna, bnb);
  k_fused1<<<dim3(B * N / 32), 256, 0, stream>>>((const uint32_t*)out, W1h, b1,
                                                 bna, bnb, out);
}

// Round 12
// 304.955 us; speedup vs baseline: 1.0655x; 1.0655x over previous
//
#include <hip/hip_runtime.h>
#include <stdint.h>

constexpr int B = 8, N = 8192, S = 2048, D1 = 128, D2 = 256;
constexpr int CIN = 384, CMID = 256, COUT = 256;

typedef __attribute__((ext_vector_type(8))) _Float16 half8;
typedef __attribute__((ext_vector_type(4))) _Float16 half4;
typedef __attribute__((ext_vector_type(4))) float f32x4;

union HU { uint32_t u; _Float16 h[2]; };

// d_out layout during the pipeline (float index (b*256+r)*8192+n):
//   rows   0..127 : hA2 (after k_interp) then h2 (after k_h) — fp16 x2 packed
//   rows 128..191 : Gt_b (k_G), fp32 [s][o]
//   rows 192..207 : k_h per-block BN partial sums
//   rows 208..231 : k_top3a candidate scratch per b: 12 d-planes at
//                   cd[(sp*3+k)*N+n], 12 idx-planes at cd+98304; consumed by
//                   k_interp's fused merge
//   rows 240..243 : (b=0 only) W0G = fp16 W0[:,0:256], written by k_wpack,
//                   read by k_G; dead after
// k_fused1 finally overwrites ALL of d_out with fp32 output.

// --------- k_wpack: all weight prepacks, launched FIRST (pw3 no longer
// exists so the ws overlay constraint is gone).
//   bid   0..63 : W1  (fp32 [256][256])      -> fp16 W1h [256][256]  (ws)
//   bid  64..95 : W0[:,256:384] (ld=384)     -> fp16 W0h [256][128]  (ws)
//   bid 96..159 : W0[:,0:256]   (ld=384)     -> fp16 W0G [256][256]  (d_out)
__global__ __launch_bounds__(256) void k_wpack(const float* __restrict__ W0,
                                               const float* __restrict__ W1,
                                               _Float16* __restrict__ W1h,
                                               _Float16* __restrict__ W0h,
                                               _Float16* __restrict__ W0G) {
  const int bid = blockIdx.x;
  if (bid < 64) {
    const int gid = bid * 256 + threadIdx.x;  // 16384 float4s
    const float4 v = *(const float4*)(W1 + (size_t)gid * 4);
    half4 h = {(_Float16)v.x, (_Float16)v.y, (_Float16)v.z, (_Float16)v.w};
    *(half4*)(W1h + (size_t)gid * 4) = h;
  } else if (bid < 96) {
    const int gid = (bid - 64) * 256 + threadIdx.x;  // 8192 float4s
    const int row = gid >> 5, c4 = gid & 31;         // 32 float4 per row
    const float4 v = *(const float4*)(W0 + (size_t)row * CIN + 256 + c4 * 4);
    half4 h = {(_Float16)v.x, (_Float16)v.y, (_Float16)v.z, (_Float16)v.w};
    *(half4*)(W0h + (size_t)row * 128 + c4 * 4) = h;
  } else {
    const int gid = (bid - 96) * 256 + threadIdx.x;  // 16384 float4s
    const int row = gid >> 6, c4 = gid & 63;         // 64 float4 per row
    const float4 v = *(const float4*)(W0 + (size_t)row * CIN + c4 * 4);
    half4 h = {(_Float16)v.x, (_Float16)v.y, (_Float16)v.z, (_Float16)v.w};
    *(half4*)(W0G + (size_t)row * 256 + c4 * 4) = h;
  }
}

// -------------------------------------------- top-3 NN, stage a (R8 final):
// grid (N/64, B, 4). Each block: 64 n × one 512-s chunk staged in 8 KB LDS as
// float4(x,y,z,|s|^2). 14.3 KB LDS + 4096 blocks -> 8 blocks/CU, 2 rounds.
// Rank key d' = |s|^2 - 2<a,s> (|a|^2 re-added in the k_interp merge).
// Closed at ~57 µs after the R9/R10/R11 variant sweep (T=2/ILP=2 all worse).
__global__ __launch_bounds__(256) void k_top3a(const float* __restrict__ xyz1,
                                               const float* __restrict__ xyz2,
                                               float* __restrict__ dout) {
  __shared__ float4 Pq[512];          // 8 KB
  __shared__ float md[4][3][64];      // 3 KB
  __shared__ int mi[4][3][64];        // 3 KB
  const int tid = threadIdx.x;
  const int wv = tid >> 6, lane = tid & 63;
  const int b = blockIdx.y;
  const int sp = blockIdx.z;          // s-split 0..3
  const int sbase = sp * 512;
  const int n = blockIdx.x * 64 + lane;
  const float* x1 = xyz1 + (size_t)b * 3 * N;
  const float* x2 = xyz2 + (size_t)b * 3 * S;

  for (int j = tid; j < 512; j += 256) {
    const int s = sbase + j;
    float sx = x2[s], sy = x2[s + S], sz = x2[s + 2 * S];
    Pq[j] = float4{sx, sy, sz, sx * sx + sy * sy + sz * sz};
  }
  const float ax = x1[n], ay = x1[n + N], az = x1[n + 2 * N];
  const float nax = -2.f * ax, nay = -2.f * ay, naz = -2.f * az;
  __syncthreads();

  float e0 = 1e30f, e1 = 1e30f, e2 = 1e30f;
  int j0 = 0, j1 = 0, j2 = 0;
  const int q0 = wv * 128, q1 = q0 + 128;   // wave's sub-range (ascending s)
#pragma unroll 8
  for (int j = q0; j < q1; ++j) {
    const float4 v = Pq[j];
    const float d = fmaf(nax, v.x, fmaf(nay, v.y, fmaf(naz, v.z, v.w)));
    const int s = sbase + j;
    // strict < : stable (lowest index wins ties)
    const bool c0 = d < e0, c1 = d < e1, c2 = d < e2;
    const int u2 = c1 ? j1 : s;
    const int u1 = c0 ? j0 : s;
    j2 = c2 ? u2 : j2;
    j1 = c1 ? u1 : j1;
    j0 = c0 ? s : j0;
    // e0<=e1<=e2 invariant: sorted-insert via 2 med3 + 1 min
    e2 = __builtin_amdgcn_fmed3f(e1, e2, d);
    e1 = __builtin_amdgcn_fmed3f(e0, e1, d);
    e0 = fminf(e0, d);
  }
  md[wv][0][lane] = e0; mi[wv][0][lane] = j0;
  md[wv][1][lane] = e1; mi[wv][1][lane] = j1;
  md[wv][2][lane] = e2; mi[wv][2][lane] = j2;
  __syncthreads();
  if (tid < 64) {
    float f0 = md[0][0][tid], f1 = md[0][1][tid], f2 = md[0][2][tid];
    int g0 = mi[0][0][tid], g1 = mi[0][1][tid], g2 = mi[0][2][tid];
#pragma unroll
    for (int w = 1; w < 4; ++w)
#pragma unroll
      for (int k = 0; k < 3; ++k) {
        float d = md[w][k][tid];
        int i = mi[w][k][tid];
        if (d < f2) {  // ascending-s wave order + strict < = stable ties
          if (d < f1) {
            f2 = f1; g2 = g1;
            if (d < f0) { f1 = f0; g1 = g0; f0 = d; g0 = i; }
            else        { f1 = d;  g1 = i; }
          } else { f2 = d; g2 = i; }
        }
      }
    // write 3 candidates (rank key d', idx) to scratch planes (rows 208..231)
    const int nm = blockIdx.x * 64 + tid;
    float* cd = dout + ((size_t)(b * 256 + 208)) * 8192;
    uint32_t* ci = (uint32_t*)cd + 98304;    // 12*8192 floats after d-planes
    cd[(sp * 3 + 0) * N + nm] = f0; ci[(sp * 3 + 0) * N + nm] = (uint32_t)g0;
    cd[(sp * 3 + 1) * N + nm] = f1; ci[(sp * 3 + 1) * N + nm] = (uint32_t)g1;
    cd[(sp * 3 + 2) * N + nm] = f2; ci[(sp * 3 + 2) * N + nm] = (uint32_t)g2;
  }
}

// ---------------------------- k_G: Gt_b[s][o] = (W0[:,0:256] @ points2_b)^T
// k_h-style rewrite: af straight from prepacked L2-resident fp16 W0G (zero
// in-loop cvt), points2 K-panel (256K x 32s, 16 KB) staged ONCE -> 2 barriers
// total (was 16). Output path (CT transpose + coalesced store) unchanged.
__global__ __launch_bounds__(256) void k_G(const float* __restrict__ points2,
                                           const _Float16* __restrict__ W0G,
                                           float* __restrict__ dout) {
  __shared__ half8 B_lds[32][32];   // 16 KB: [kc=k/8][s]
  __shared__ float CT[32][258];     // 33 KB
  const int tid = threadIdx.x;
  const int b = blockIdx.x >> 6;
  const int s0 = (blockIdx.x & 63) * 32;
  f32x4 acc[4][2] = {};
  const int wv = tid >> 6, lane = tid & 63;
  const int ln = lane & 15, quad = lane >> 4;
  const int bn = tid & 31, kc0 = tid >> 5;

#pragma unroll
  for (int it = 0; it < 4; ++it) {
    const int kc = kc0 + 8 * it;        // 0..31
    half8 hv;
#pragma unroll
    for (int j = 0; j < 8; ++j)
      hv[j] = (_Float16)points2[((size_t)(b * 256 + kc * 8 + j)) * S + s0 + bn];
    B_lds[kc][bn] = hv;
  }
  __syncthreads();
  for (int kk = 0; kk < 256; kk += 32) {
    half8 af[4], bf[2];
#pragma unroll
    for (int i = 0; i < 4; ++i) {
      const int row = wv * 64 + i * 16 + ln;
      af[i] = *(const half8*)(W0G + (size_t)row * 256 + kk + quad * 8);
    }
#pragma unroll
    for (int j = 0; j < 2; ++j)
      bf[j] = B_lds[(kk >> 3) + quad][j * 16 + ln];
#pragma unroll
    for (int i = 0; i < 4; ++i)
#pragma unroll
      for (int j = 0; j < 2; ++j)
        acc[i][j] = __builtin_amdgcn_mfma_f32_16x16x32_f16(af[i], bf[j], acc[i][j], 0, 0, 0);
  }
#pragma unroll
  for (int i = 0; i < 4; ++i)
#pragma unroll
    for (int reg = 0; reg < 4; ++reg) {
      int row = wv * 64 + i * 16 + quad * 4 + reg;
#pragma unroll
      for (int j = 0; j < 2; ++j) CT[j * 16 + ln][row] = acc[i][j][reg];
    }
  __syncthreads();
  const int sl = tid >> 3, g = tid & 7;
  float* g0 = dout + ((size_t)(b * 256 + 128)) * 8192 + (size_t)(s0 + sl) * 256 + g * 32;
#pragma unroll
  for (int q = 0; q < 8; ++q)
    *(float4*)(g0 + q * 4) = *(const float4*)&CT[sl][g * 32 + q * 4];
}

// --------------- k_interp (now with fused top3 merge): per block of 32 n,
// threads 0..31 fold the 12 scratch candidates for their n (ascending split =
// ascending s-range -> strict < keeps lowest-index ties), add |x1|^2, compute
// fp32 weights (quantization gone) -> LDS; then the gather/interp as before.
__global__ __launch_bounds__(256) void k_interp(const float* __restrict__ xyz1,
                                                const float* __restrict__ dout_c,
                                                uint32_t* __restrict__ dout_u) {
  __shared__ int sidx[96];
  __shared__ float sw[96];
  const int tid = threadIdx.x;
  const int b = blockIdx.x >> 8;
  const int n0 = (blockIdx.x & 255) * 32;
  if (tid < 32) {
    const int n = n0 + tid;
    const float* cd = dout_c + ((size_t)(b * 256 + 208)) * 8192;
    const uint32_t* ci = (const uint32_t*)cd + 98304;
    float f0 = 1e30f, f1 = 1e30f, f2 = 1e30f;
    int g0 = 0, g1 = 0, g2 = 0;
#pragma unroll
    for (int t = 0; t < 12; ++t) {
      float d = cd[(size_t)t * N + n];
      int i = (int)ci[(size_t)t * N + n];
      if (d < f2) {
        if (d < f1) {
          f2 = f1; g2 = g1;
          if (d < f0) { f1 = f0; g1 = g0; f0 = d; g0 = i; }
          else        { f1 = d;  g1 = i; }
        } else { f2 = d; g2 = i; }
      }
    }
    const float* x1 = xyz1 + (size_t)b * 3 * N;
    const float ax = x1[n], ay = x1[n + N], az = x1[n + 2 * N];
    const float rn = ax * ax + ay * ay + az * az;
    // recover true squared distances (clamp: fp rounding can go slightly neg)
    float q0 = fmaxf(f0 + rn, 0.f);
    float q1 = fmaxf(f1 + rn, 0.f);
    float q2 = fmaxf(f2 + rn, 0.f);
    float r0 = 1.0f / (q0 + 1e-8f), r1 = 1.0f / (q1 + 1e-8f), r2 = 1.0f / (q2 + 1e-8f);
    float inv = 1.0f / (r0 + r1 + r2);
    sidx[tid * 3 + 0] = g0; sw[tid * 3 + 0] = r0 * inv;
    sidx[tid * 3 + 1] = g1; sw[tid * 3 + 1] = r1 * inv;
    sidx[tid * 3 + 2] = g2; sw[tid * 3 + 2] = r2 * inv;
  }
  __syncthreads();
  const int colL = tid >> 3, p = tid & 7;  // 8 lanes/col, 32 channels each
  const float* Gb = dout_c + ((size_t)(b * 256 + 128)) * 8192;
  float a[32];
#pragma unroll
  for (int q = 0; q < 32; ++q) a[q] = 0.f;
#pragma unroll
  for (int k = 0; k < 3; ++k) {
    int j = sidx[colL * 3 + k];
    float w = sw[colL * 3 + k];
    const float* g = Gb + (size_t)j * 256 + p * 32;
#pragma unroll
    for (int q = 0; q < 8; ++q) {
      float4 v = *(const float4*)(g + q * 4);
      a[q * 4 + 0] += w * v.x; a[q * 4 + 1] += w * v.y;
      a[q * 4 + 2] += w * v.z; a[q * 4 + 3] += w * v.w;
    }
  }
#pragma unroll
  for (int q = 0; q < 16; ++q) {
    int cp = p * 16 + q;
    HU u;
    u.h[0] = (_Float16)a[2 * q];
    u.h[1] = (_Float16)a[2 * q + 1];
    dout_u[((size_t)(b * 256 + cp)) * 8192 + n0 + colL] = u.u;
  }
}

// ------- k_h: h = hA + W0[:,256:384]@p1 + b0; write packed fp16 h2 in place
// over hA2; emit per-block BN partials into d_out rows 192..207.
__global__ __launch_bounds__(256) void k_h(uint32_t* __restrict__ h2,
                                           float* __restrict__ dpart,
                                           const float* __restrict__ points1,
                                           const _Float16* __restrict__ W0h,
                                           const float* __restrict__ b0) {
  __shared__ half8 B_lds[16][32];   // 8 KB: [K-chunk(8K)][col]
  __shared__ float red_s[256], red_q[256], sb0[256];
  const int tid = threadIdx.x;
  const int b = blockIdx.x >> 8;
  const int cb = blockIdx.x & 255;
  const int n0 = cb * 32;
  sb0[tid] = b0[tid];
  const int wv = tid >> 6, lane = tid & 63;
  const int ln = lane & 15, quad = lane >> 4;

  // ---- init acc = hA (C-in); loads issue first, waited at first MFMA
  f32x4 acc[4][2];
#pragma unroll
  for (int i = 0; i < 4; ++i) {
    const int rb = wv * 64 + i * 16 + quad * 4;
    const int cp0 = rb >> 1;
#pragma unroll
    for (int j = 0; j < 2; ++j) {
      const int col = n0 + j * 16 + ln;
      const size_t a0 = ((size_t)(b * 256 + cp0)) * 8192 + col;
      HU ua, ub;
      ua.u = h2[a0];
      ub.u = h2[a0 + 8192];
      acc[i][j][0] = (float)ua.h[0];
      acc[i][j][1] = (float)ua.h[1];
      acc[i][j][2] = (float)ub.h[0];
      acc[i][j][3] = (float)ub.h[1];
    }
  }
  // ---- stage points1 [128K][32cols] -> fp16 LDS (one barrier total)
  {
    const int col = tid & 31;
    const int kc0 = tid >> 5;           // 0..7
#pragma unroll
    for (int it = 0; it < 2; ++it) {
      const int kc = kc0 + 8 * it;      // 0..15
      half8 hv;
#pragma unroll
      for (int j = 0; j < 8; ++j)
        hv[j] = (_Float16)points1[((size_t)(b * D1 + kc * 8 + j)) * N + n0 + col];
      B_lds[kc][col] = hv;
    }
  }
  __syncthreads();
  // ---- sync-free K-loop, af straight from global W0h
  for (int kk = 0; kk < 128; kk += 32) {
    half8 af[4], bf[2];
#pragma unroll
    for (int i = 0; i < 4; ++i) {
      const int row = wv * 64 + i * 16 + ln;
      af[i] = *(const half8*)(W0h + (size_t)row * 128 + kk + quad * 8);
    }
#pragma unroll
    for (int j = 0; j < 2; ++j)
      bf[j] = B_lds[(kk >> 3) + quad][j * 16 + ln];
#pragma unroll
    for (int i = 0; i < 4; ++i)
#pragma unroll
      for (int j = 0; j < 2; ++j)
        acc[i][j] = __builtin_amdgcn_mfma_f32_16x16x32_f16(af[i], bf[j], acc[i][j], 0, 0, 0);
  }
  // ---- epilogue: +b0, round fp16, store in place, accumulate row sums
#pragma unroll
  for (int i = 0; i < 4; ++i) {
    const int rb = wv * 64 + i * 16 + quad * 4;
    const int cp0 = rb >> 1;
    float rs[4] = {0.f, 0.f, 0.f, 0.f}, rq[4] = {0.f, 0.f, 0.f, 0.f};
#pragma unroll
    for (int j = 0; j < 2; ++j) {
      const int col = n0 + j * 16 + ln;
      const size_t a0 = ((size_t)(b * 256 + cp0)) * 8192 + col;
      _Float16 e0 = (_Float16)(acc[i][j][0] + sb0[rb + 0]);
      _Float16 e1 = (_Float16)(acc[i][j][1] + sb0[rb + 1]);
      _Float16 e2 = (_Float16)(acc[i][j][2] + sb0[rb + 2]);
      _Float16 e3 = (_Float16)(acc[i][j][3] + sb0[rb + 3]);
      HU o0, o1;
      o0.h[0] = e0; o0.h[1] = e1; o1.h[0] = e2; o1.h[1] = e3;
      h2[a0] = o0.u;
      h2[a0 + 8192] = o1.u;
      float f0 = (float)e0, f1 = (float)e1, f2 = (float)e2, f3 = (float)e3;
      rs[0] += f0; rq[0] += f0 * f0;
      rs[1] += f1; rq[1] += f1 * f1;
      rs[2] += f2; rq[2] += f2 * f2;
      rs[3] += f3; rq[3] += f3 * f3;
    }
#pragma unroll
    for (int reg = 0; reg < 4; ++reg) {
      float s = rs[reg], q = rq[reg];
#pragma unroll
      for (int m = 1; m < 16; m <<= 1) {
        s += __shfl_xor(s, m);
        q += __shfl_xor(q, m);
      }
      if (ln == 0) { red_s[rb + reg] = s; red_q[rb + reg] = q; }
    }
  }
  __syncthreads();
  float* part = dpart + ((size_t)(b * 256 + 192)) * 8192 + (size_t)cb * 512;
  part[tid] = red_s[tid];
  part[256 + tid] = red_q[tid];
}

// ------------------------- k_bn: reduce 2048 partials/channel -> a,b per chan
__global__ __launch_bounds__(256) void k_bn(const float* __restrict__ dpart,
                                            const float* __restrict__ gamma,
                                            const float* __restrict__ beta,
                                            float* __restrict__ bna,
                                            float* __restrict__ bnb) {
  const int c = blockIdx.x;
  const int tid = threadIdx.x;
  float s = 0.f, q = 0.f;
#pragma unroll
  for (int u = tid; u < 2048; u += 256) {
    int b = u >> 8, cb = u & 255;
    const float* part = dpart + ((size_t)(b * 256 + 192)) * 8192 + (size_t)cb * 512;
    s += part[c];
    q += part[256 + c];
  }
#pragma unroll
  for (int m = 1; m < 64; m <<= 1) {
    s += __shfl_xor(s, m);
    q += __shfl_xor(q, m);
  }
  __shared__ float ls[4], lq[4];
  if ((tid & 63) == 0) { ls[tid >> 6] = s; lq[tid >> 6] = q; }
  __syncthreads();
  if (tid == 0) {
    float st = ls[0] + ls[1] + ls[2] + ls[3];
    float qt = lq[0] + lq[1] + lq[2] + lq[3];
    const float invn = 1.0f / (float)(B * N);
    float mean = st * invn;
    float var = qt * invn - mean * mean;  // biased, matches reference
    float a = gamma[c] * rsqrtf(var + 1e-5f);
    bna[c] = a;
    bnb[c] = beta[c] - mean * a;
  }
}

// ------- k_fused1: out = relu(W1 @ relu(a*h+b) + b1), fp32 over all of d_out.
__global__ __launch_bounds__(256) void k_fused1(const uint32_t* h2,
                                                const _Float16* __restrict__ W1h,
                                                const float* __restrict__ b1,
                                                const float* __restrict__ bna,
                                                const float* __restrict__ bnb,
                                                float* out) {
  __shared__ uint32_t Hh[32 * 33 * 4];  // [kc][col(+1 pad)][k&7] halfs, 16.9 KB
  __shared__ float sa[256], sb[256], sb1[256];
  const int tid = threadIdx.x;
  const int b = blockIdx.x >> 8;
  const int n0 = (blockIdx.x & 255) * 32;
  sa[tid] = bna[tid]; sb[tid] = bnb[tid]; sb1[tid] = b1[tid];
  __syncthreads();
  {
    // 128 packed rows x 32 cols; each thread: 4 x uint4 (4 cols x 4 cps)
    const int c4 = tid & 7;          // col group: cols c4*4 .. c4*4+3
    const int rg = tid >> 3;         // 0..31
#pragma unroll
    for (int q = 0; q < 4; ++q) {
      const int cp = rg + 32 * q;    // 0..127
      const uint4 v = *(const uint4*)&h2[((size_t)(b * 256 + cp)) * 8192 + n0 + c4 * 4];
      const int k0 = 2 * cp;
      const float a0 = sa[k0], a1 = sa[k0 + 1], b0v = sb[k0], b1v = sb[k0 + 1];
      const int kc = cp >> 2, sub = cp & 3;
      const uint32_t vv[4] = {v.x, v.y, v.z, v.w};
#pragma unroll
      for (int m = 0; m < 4; ++m) {
        HU u; u.u = vv[m];
        float v0 = a0 * (float)u.h[0] + b0v;
        float v1 = a1 * (float)u.h[1] + b1v;
        HU o;
        o.h[0] = (_Float16)(v0 > 0.f ? v0 : 0.f);
        o.h[1] = (_Float16)(v1 > 0.f ? v1 : 0.f);
        Hh[((kc * 33) + c4 * 4 + m) * 4 + sub] = o.u;
      }
    }
  }
  __syncthreads();
  f32x4 acc[4][2] = {};
  const int wv = tid >> 6, lane = tid & 63;
  const int ln = lane & 15, quad = lane >> 4;
  for (int kk = 0; kk < 256; kk += 32) {
    half8 af[4], bf[2];
#pragma unroll
    for (int i = 0; i < 4; ++i) {
      int row = wv * 64 + i * 16 + ln;
      af[i] = *(const half8*)(W1h + (size_t)row * CMID + kk + quad * 8);
    }
#pragma unroll
    for (int j = 0; j < 2; ++j)
      bf[j] = *(const half8*)&Hh[(((kk >> 3) + quad) * 33 + j * 16 + ln) * 4];
#pragma unroll
    for (int i = 0; i < 4; ++i)
#pragma unroll
      for (int j = 0; j < 2; ++j)
        acc[i][j] = __builtin_amdgcn_mfma_f32_16x16x32_f16(af[i], bf[j], acc[i][j], 0, 0, 0);
  }
#pragma unroll
  for (int i = 0; i < 4; ++i) {
    const int rb = wv * 64 + i * 16 + quad * 4;
#pragma unroll
    for (int reg = 0; reg < 4; ++reg) {
      int row = rb + reg;
      float bias = sb1[row];
      float* orow = out + ((size_t)(b * 256 + row)) * 8192 + n0;
#pragma unroll
      for (int j = 0; j < 2; ++j)
        orow[j * 16 + ln] = fmaxf(acc[i][j][reg] + bias, 0.f);
    }
  }
}

extern "C" void kernel_launch(void* const* d_in, const int* in_sizes, int n_in,
                              void* d_out, int out_size, void* d_ws, size_t ws_size,
                              hipStream_t stream) {
  const float* xyz1 = (const float*)d_in[0];
  const float* xyz2 = (const float*)d_in[1];
  const float* points1 = (const float*)d_in[2];
  const float* points2 = (const float*)d_in[3];
  const float* W0 = (const float*)d_in[4];
  const float* b0 = (const float*)d_in[5];
  const float* gamma0 = (const float*)d_in[6];
  const float* beta0 = (const float*)d_in[7];
  const float* W1 = (const float*)d_in[8];
  const float* b1 = (const float*)d_in[9];
  float* out = (float*)d_out;

  // ws layout (788,480 B == R1's proven-safe size; do NOT grow):
  //   [0,1K) bna | [1K,2K) bnb | [2K..) W1h (128 KB) + W0h (64 KB)
  // (pw3 is gone — the top3 merge is fused into k_interp via d_out scratch.)
  char* ws = (char*)d_ws;
  float* bna = (float*)ws;
  float* bnb = (float*)(ws + 1024);
  _Float16* W1h = (_Float16*)(ws + 2048);
  _Float16* W0h = (_Float16*)(ws + 2048 + 131072);
  // W0G lives in d_out rows 240..243 of b=0 (dead until k_fused1's final
  // overwrite; k_G consumes it before anything else touches that region).
  _Float16* W0G = (_Float16*)(out + (size_t)240 * 8192);

  k_wpack<<<dim3(160), 256, 0, stream>>>(W0, W1, W1h, W0h, W0G);
  k_top3a<<<dim3(N / 64, B, 4), 256, 0, stream>>>(xyz1, xyz2, out);
  k_G<<<dim3(B * 64), 256, 0, stream>>>(points2, W0G, out);
  k_interp<<<dim3(B * N / 32), 256, 0, stream>>>(xyz1, out, (uint32_t*)out);
  k_h<<<dim3(B * N / 32), 256, 0, stream>>>((uint32_t*)out, out, points1, W0h, b0);
  k_bn<<<dim3(256), 256, 0, stream>>>(out, gamma0, beta0, bna, bnb);
  k_fused1<<<dim3(B * N / 32), 256, 0, stream>>>((const uint32_t*)out, W1h, b1,
                                                 bna, bnb, out);
}

// Round 13
// 304.659 us; speedup vs baseline: 1.0665x; 1.0010x over previous
//
#include <hip/hip_runtime.h>
#include <stdint.h>

constexpr int B = 8, N = 8192, S = 2048, D1 = 128, D2 = 256;
constexpr int CIN = 384, CMID = 256, COUT = 256;

typedef __attribute__((ext_vector_type(8))) _Float16 half8;
typedef __attribute__((ext_vector_type(4))) _Float16 half4;
typedef __attribute__((ext_vector_type(4))) float f32x4;

union HU { uint32_t u; _Float16 h[2]; };

// d_out layout during the pipeline (float index (b*256+r)*8192+n):
//   rows   0..127 : hA2 (after k_interp) then h2 (after k_h) — fp16 x2 packed
//   rows 128..191 : Gt_b (k_G), fp32 [s][o]
//   rows 192..207 : k_h per-block BN partial sums
//   rows 208..231 : k_top3a candidate scratch per b: 12 d-planes at
//                   cd[(sp*3+k)*N+n], 12 idx-planes at cd+98304; consumed by
//                   k_interp's fused merge
//   rows 240..243 : (b=0 only) W0G = fp16 W0[:,0:256], written by k_wpack,
//                   read by k_G; dead after
// k_fused1 finally overwrites ALL of d_out with fp32 output.
//
// XCD affinity (R13): k_G and k_interp both map b = blockIdx.x & 7 so batch
// b's Gt (2 MB) is produced AND consumed on XCD b (round-robin dispatch) —
// the gather's 192 MB of logical re-reads become L2-resident. Heuristic
// only; correctness does not depend on the mapping.

// --------- k_wpack: all weight prepacks, launched FIRST.
//   bid   0..63 : W1  (fp32 [256][256])      -> fp16 W1h [256][256]  (ws)
//   bid  64..95 : W0[:,256:384] (ld=384)     -> fp16 W0h [256][128]  (ws)
//   bid 96..159 : W0[:,0:256]   (ld=384)     -> fp16 W0G [256][256]  (d_out)
__global__ __launch_bounds__(256) void k_wpack(const float* __restrict__ W0,
                                               const float* __restrict__ W1,
                                               _Float16* __restrict__ W1h,
                                               _Float16* __restrict__ W0h,
                                               _Float16* __restrict__ W0G) {
  const int bid = blockIdx.x;
  if (bid < 64) {
    const int gid = bid * 256 + threadIdx.x;  // 16384 float4s
    const float4 v = *(const float4*)(W1 + (size_t)gid * 4);
    half4 h = {(_Float16)v.x, (_Float16)v.y, (_Float16)v.z, (_Float16)v.w};
    *(half4*)(W1h + (size_t)gid * 4) = h;
  } else if (bid < 96) {
    const int gid = (bid - 64) * 256 + threadIdx.x;  // 8192 float4s
    const int row = gid >> 5, c4 = gid & 31;         // 32 float4 per row
    const float4 v = *(const float4*)(W0 + (size_t)row * CIN + 256 + c4 * 4);
    half4 h = {(_Float16)v.x, (_Float16)v.y, (_Float16)v.z, (_Float16)v.w};
    *(half4*)(W0h + (size_t)row * 128 + c4 * 4) = h;
  } else {
    const int gid = (bid - 96) * 256 + threadIdx.x;  // 16384 float4s
    const int row = gid >> 6, c4 = gid & 63;         // 64 float4 per row
    const float4 v = *(const float4*)(W0 + (size_t)row * CIN + c4 * 4);
    half4 h = {(_Float16)v.x, (_Float16)v.y, (_Float16)v.z, (_Float16)v.w};
    *(half4*)(W0G + (size_t)row * 256 + c4 * 4) = h;
  }
}

// -------------------------------------------- top-3 NN, stage a (R8 final):
// grid (N/64, B, 4). Each block: 64 n × one 512-s chunk staged in 8 KB LDS as
// float4(x,y,z,|s|^2). 14.3 KB LDS + 4096 blocks -> 8 blocks/CU, 2 rounds.
// Rank key d' = |s|^2 - 2<a,s> (|a|^2 re-added in the k_interp merge).
// Closed at ~57 µs after the R9/R10/R11 variant sweep (T=2/ILP=2 all worse).
__global__ __launch_bounds__(256) void k_top3a(const float* __restrict__ xyz1,
                                               const float* __restrict__ xyz2,
                                               float* __restrict__ dout) {
  __shared__ float4 Pq[512];          // 8 KB
  __shared__ float md[4][3][64];      // 3 KB
  __shared__ int mi[4][3][64];        // 3 KB
  const int tid = threadIdx.x;
  const int wv = tid >> 6, lane = tid & 63;
  const int b = blockIdx.y;
  const int sp = blockIdx.z;          // s-split 0..3
  const int sbase = sp * 512;
  const int n = blockIdx.x * 64 + lane;
  const float* x1 = xyz1 + (size_t)b * 3 * N;
  const float* x2 = xyz2 + (size_t)b * 3 * S;

  for (int j = tid; j < 512; j += 256) {
    const int s = sbase + j;
    float sx = x2[s], sy = x2[s + S], sz = x2[s + 2 * S];
    Pq[j] = float4{sx, sy, sz, sx * sx + sy * sy + sz * sz};
  }
  const float ax = x1[n], ay = x1[n + N], az = x1[n + 2 * N];
  const float nax = -2.f * ax, nay = -2.f * ay, naz = -2.f * az;
  __syncthreads();

  float e0 = 1e30f, e1 = 1e30f, e2 = 1e30f;
  int j0 = 0, j1 = 0, j2 = 0;
  const int q0 = wv * 128, q1 = q0 + 128;   // wave's sub-range (ascending s)
#pragma unroll 8
  for (int j = q0; j < q1; ++j) {
    const float4 v = Pq[j];
    const float d = fmaf(nax, v.x, fmaf(nay, v.y, fmaf(naz, v.z, v.w)));
    const int s = sbase + j;
    // strict < : stable (lowest index wins ties)
    const bool c0 = d < e0, c1 = d < e1, c2 = d < e2;
    const int u2 = c1 ? j1 : s;
    const int u1 = c0 ? j0 : s;
    j2 = c2 ? u2 : j2;
    j1 = c1 ? u1 : j1;
    j0 = c0 ? s : j0;
    // e0<=e1<=e2 invariant: sorted-insert via 2 med3 + 1 min
    e2 = __builtin_amdgcn_fmed3f(e1, e2, d);
    e1 = __builtin_amdgcn_fmed3f(e0, e1, d);
    e0 = fminf(e0, d);
  }
  md[wv][0][lane] = e0; mi[wv][0][lane] = j0;
  md[wv][1][lane] = e1; mi[wv][1][lane] = j1;
  md[wv][2][lane] = e2; mi[wv][2][lane] = j2;
  __syncthreads();
  if (tid < 64) {
    float f0 = md[0][0][tid], f1 = md[0][1][tid], f2 = md[0][2][tid];
    int g0 = mi[0][0][tid], g1 = mi[0][1][tid], g2 = mi[0][2][tid];
#pragma unroll
    for (int w = 1; w < 4; ++w)
#pragma unroll
      for (int k = 0; k < 3; ++k) {
        float d = md[w][k][tid];
        int i = mi[w][k][tid];
        if (d < f2) {  // ascending-s wave order + strict < = stable ties
          if (d < f1) {
            f2 = f1; g2 = g1;
            if (d < f0) { f1 = f0; g1 = g0; f0 = d; g0 = i; }
            else        { f1 = d;  g1 = i; }
          } else { f2 = d; g2 = i; }
        }
      }
    // write 3 candidates (rank key d', idx) to scratch planes (rows 208..231)
    const int nm = blockIdx.x * 64 + tid;
    float* cd = dout + ((size_t)(b * 256 + 208)) * 8192;
    uint32_t* ci = (uint32_t*)cd + 98304;    // 12*8192 floats after d-planes
    cd[(sp * 3 + 0) * N + nm] = f0; ci[(sp * 3 + 0) * N + nm] = (uint32_t)g0;
    cd[(sp * 3 + 1) * N + nm] = f1; ci[(sp * 3 + 1) * N + nm] = (uint32_t)g1;
    cd[(sp * 3 + 2) * N + nm] = f2; ci[(sp * 3 + 2) * N + nm] = (uint32_t)g2;
  }
}

// ---------------------------- k_G: Gt_b[s][o] = (W0[:,0:256] @ points2_b)^T
// af straight from prepacked L2-resident fp16 W0G, points2 K-panel staged
// once -> 2 barriers. XCD affinity: b = bid & 7 (Gt_b written on XCD b).
__global__ __launch_bounds__(256) void k_G(const float* __restrict__ points2,
                                           const _Float16* __restrict__ W0G,
                                           float* __restrict__ dout) {
  __shared__ half8 B_lds[32][32];   // 16 KB: [kc=k/8][s]
  __shared__ float CT[32][258];     // 33 KB
  const int tid = threadIdx.x;
  const int b = blockIdx.x & 7;
  const int s0 = (blockIdx.x >> 3) * 32;
  f32x4 acc[4][2] = {};
  const int wv = tid >> 6, lane = tid & 63;
  const int ln = lane & 15, quad = lane >> 4;
  const int bn = tid & 31, kc0 = tid >> 5;

#pragma unroll
  for (int it = 0; it < 4; ++it) {
    const int kc = kc0 + 8 * it;        // 0..31
    half8 hv;
#pragma unroll
    for (int j = 0; j < 8; ++j)
      hv[j] = (_Float16)points2[((size_t)(b * 256 + kc * 8 + j)) * S + s0 + bn];
    B_lds[kc][bn] = hv;
  }
  __syncthreads();
  for (int kk = 0; kk < 256; kk += 32) {
    half8 af[4], bf[2];
#pragma unroll
    for (int i = 0; i < 4; ++i) {
      const int row = wv * 64 + i * 16 + ln;
      af[i] = *(const half8*)(W0G + (size_t)row * 256 + kk + quad * 8);
    }
#pragma unroll
    for (int j = 0; j < 2; ++j)
      bf[j] = B_lds[(kk >> 3) + quad][j * 16 + ln];
#pragma unroll
    for (int i = 0; i < 4; ++i)
#pragma unroll
      for (int j = 0; j < 2; ++j)
        acc[i][j] = __builtin_amdgcn_mfma_f32_16x16x32_f16(af[i], bf[j], acc[i][j], 0, 0, 0);
  }
#pragma unroll
  for (int i = 0; i < 4; ++i)
#pragma unroll
    for (int reg = 0; reg < 4; ++reg) {
      int row = wv * 64 + i * 16 + quad * 4 + reg;
#pragma unroll
      for (int j = 0; j < 2; ++j) CT[j * 16 + ln][row] = acc[i][j][reg];
    }
  __syncthreads();
  const int sl = tid >> 3, g = tid & 7;
  float* g0 = dout + ((size_t)(b * 256 + 128)) * 8192 + (size_t)(s0 + sl) * 256 + g * 32;
#pragma unroll
  for (int q = 0; q < 8; ++q)
    *(float4*)(g0 + q * 4) = *(const float4*)&CT[sl][g * 32 + q * 4];
}

// --------------- k_interp (fused top3 merge): per block of 32 n, threads
// 0..31 fold the 12 scratch candidates for their n, add |x1|^2, fp32 weights
// -> LDS; then the gather/interp. XCD affinity: b = bid & 7 so the gather
// hits the same XCD L2 that k_G left Gt_b in.
__global__ __launch_bounds__(256) void k_interp(const float* __restrict__ xyz1,
                                                const float* __restrict__ dout_c,
                                                uint32_t* __restrict__ dout_u) {
  __shared__ int sidx[96];
  __shared__ float sw[96];
  const int tid = threadIdx.x;
  const int b = blockIdx.x & 7;
  const int n0 = (blockIdx.x >> 3) * 32;
  if (tid < 32) {
    const int n = n0 + tid;
    const float* cd = dout_c + ((size_t)(b * 256 + 208)) * 8192;
    const uint32_t* ci = (const uint32_t*)cd + 98304;
    float f0 = 1e30f, f1 = 1e30f, f2 = 1e30f;
    int g0 = 0, g1 = 0, g2 = 0;
#pragma unroll
    for (int t = 0; t < 12; ++t) {
      float d = cd[(size_t)t * N + n];
      int i = (int)ci[(size_t)t * N + n];
      if (d < f2) {
        if (d < f1) {
          f2 = f1; g2 = g1;
          if (d < f0) { f1 = f0; g1 = g0; f0 = d; g0 = i; }
          else        { f1 = d;  g1 = i; }
        } else { f2 = d; g2 = i; }
      }
    }
    const float* x1 = xyz1 + (size_t)b * 3 * N;
    const float ax = x1[n], ay = x1[n + N], az = x1[n + 2 * N];
    const float rn = ax * ax + ay * ay + az * az;
    // recover true squared distances (clamp: fp rounding can go slightly neg)
    float q0 = fmaxf(f0 + rn, 0.f);
    float q1 = fmaxf(f1 + rn, 0.f);
    float q2 = fmaxf(f2 + rn, 0.f);
    float r0 = 1.0f / (q0 + 1e-8f), r1 = 1.0f / (q1 + 1e-8f), r2 = 1.0f / (q2 + 1e-8f);
    float inv = 1.0f / (r0 + r1 + r2);
    sidx[tid * 3 + 0] = g0; sw[tid * 3 + 0] = r0 * inv;
    sidx[tid * 3 + 1] = g1; sw[tid * 3 + 1] = r1 * inv;
    sidx[tid * 3 + 2] = g2; sw[tid * 3 + 2] = r2 * inv;
  }
  __syncthreads();
  const int colL = tid >> 3, p = tid & 7;  // 8 lanes/col, 32 channels each
  const float* Gb = dout_c + ((size_t)(b * 256 + 128)) * 8192;
  float a[32];
#pragma unroll
  for (int q = 0; q < 32; ++q) a[q] = 0.f;
#pragma unroll
  for (int k = 0; k < 3; ++k) {
    int j = sidx[colL * 3 + k];
    float w = sw[colL * 3 + k];
    const float* g = Gb + (size_t)j * 256 + p * 32;
#pragma unroll
    for (int q = 0; q < 8; ++q) {
      float4 v = *(const float4*)(g + q * 4);
      a[q * 4 + 0] += w * v.x; a[q * 4 + 1] += w * v.y;
      a[q * 4 + 2] += w * v.z; a[q * 4 + 3] += w * v.w;
    }
  }
#pragma unroll
  for (int q = 0; q < 16; ++q) {
    int cp = p * 16 + q;
    HU u;
    u.h[0] = (_Float16)a[2 * q];
    u.h[1] = (_Float16)a[2 * q + 1];
    dout_u[((size_t)(b * 256 + cp)) * 8192 + n0 + colL] = u.u;
  }
}

// ------- k_h: h = hA + W0[:,256:384]@p1 + b0; write packed fp16 h2 in place
// over hA2; emit per-block BN partials into d_out rows 192..207.
__global__ __launch_bounds__(256) void k_h(uint32_t* __restrict__ h2,
                                           float* __restrict__ dpart,
                                           const float* __restrict__ points1,
                                           const _Float16* __restrict__ W0h,
                                           const float* __restrict__ b0) {
  __shared__ half8 B_lds[16][32];   // 8 KB: [K-chunk(8K)][col]
  __shared__ float red_s[256], red_q[256], sb0[256];
  const int tid = threadIdx.x;
  const int b = blockIdx.x >> 8;
  const int cb = blockIdx.x & 255;
  const int n0 = cb * 32;
  sb0[tid] = b0[tid];
  const int wv = tid >> 6, lane = tid & 63;
  const int ln = lane & 15, quad = lane >> 4;

  // ---- init acc = hA (C-in); loads issue first, waited at first MFMA
  f32x4 acc[4][2];
#pragma unroll
  for (int i = 0; i < 4; ++i) {
    const int rb = wv * 64 + i * 16 + quad * 4;
    const int cp0 = rb >> 1;
#pragma unroll
    for (int j = 0; j < 2; ++j) {
      const int col = n0 + j * 16 + ln;
      const size_t a0 = ((size_t)(b * 256 + cp0)) * 8192 + col;
      HU ua, ub;
      ua.u = h2[a0];
      ub.u = h2[a0 + 8192];
      acc[i][j][0] = (float)ua.h[0];
      acc[i][j][1] = (float)ua.h[1];
      acc[i][j][2] = (float)ub.h[0];
      acc[i][j][3] = (float)ub.h[1];
    }
  }
  // ---- stage points1 [128K][32cols] -> fp16 LDS (one barrier total)
  {
    const int col = tid & 31;
    const int kc0 = tid >> 5;           // 0..7
#pragma unroll
    for (int it = 0; it < 2; ++it) {
      const int kc = kc0 + 8 * it;      // 0..15
      half8 hv;
#pragma unroll
      for (int j = 0; j < 8; ++j)
        hv[j] = (_Float16)points1[((size_t)(b * D1 + kc * 8 + j)) * N + n0 + col];
      B_lds[kc][col] = hv;
    }
  }
  __syncthreads();
  // ---- sync-free K-loop, af straight from global W0h
  for (int kk = 0; kk < 128; kk += 32) {
    half8 af[4], bf[2];
#pragma unroll
    for (int i = 0; i < 4; ++i) {
      const int row = wv * 64 + i * 16 + ln;
      af[i] = *(const half8*)(W0h + (size_t)row * 128 + kk + quad * 8);
    }
#pragma unroll
    for (int j = 0; j < 2; ++j)
      bf[j] = B_lds[(kk >> 3) + quad][j * 16 + ln];
#pragma unroll
    for (int i = 0; i < 4; ++i)
#pragma unroll
      for (int j = 0; j < 2; ++j)
        acc[i][j] = __builtin_amdgcn_mfma_f32_16x16x32_f16(af[i], bf[j], acc[i][j], 0, 0, 0);
  }
  // ---- epilogue: +b0, round fp16, store in place, accumulate row sums
#pragma unroll
  for (int i = 0; i < 4; ++i) {
    const int rb = wv * 64 + i * 16 + quad * 4;
    const int cp0 = rb >> 1;
    float rs[4] = {0.f, 0.f, 0.f, 0.f}, rq[4] = {0.f, 0.f, 0.f, 0.f};
#pragma unroll
    for (int j = 0; j < 2; ++j) {
      const int col = n0 + j * 16 + ln;
      const size_t a0 = ((size_t)(b * 256 + cp0)) * 8192 + col;
      _Float16 e0 = (_Float16)(acc[i][j][0] + sb0[rb + 0]);
      _Float16 e1 = (_Float16)(acc[i][j][1] + sb0[rb + 1]);
      _Float16 e2 = (_Float16)(acc[i][j][2] + sb0[rb + 2]);
      _Float16 e3 = (_Float16)(acc[i][j][3] + sb0[rb + 3]);
      HU o0, o1;
      o0.h[0] = e0; o0.h[1] = e1; o1.h[0] = e2; o1.h[1] = e3;
      h2[a0] = o0.u;
      h2[a0 + 8192] = o1.u;
      float f0 = (float)e0, f1 = (float)e1, f2 = (float)e2, f3 = (float)e3;
      rs[0] += f0; rq[0] += f0 * f0;
      rs[1] += f1; rq[1] += f1 * f1;
      rs[2] += f2; rq[2] += f2 * f2;
      rs[3] += f3; rq[3] += f3 * f3;
    }
#pragma unroll
    for (int reg = 0; reg < 4; ++reg) {
      float s = rs[reg], q = rq[reg];
#pragma unroll
      for (int m = 1; m < 16; m <<= 1) {
        s += __shfl_xor(s, m);
        q += __shfl_xor(q, m);
      }
      if (ln == 0) { red_s[rb + reg] = s; red_q[rb + reg] = q; }
    }
  }
  __syncthreads();
  float* part = dpart + ((size_t)(b * 256 + 192)) * 8192 + (size_t)cb * 512;
  part[tid] = red_s[tid];
  part[256 + tid] = red_q[tid];
}

// ------------------------- k_bn: reduce 2048 partials/channel -> a,b per chan
__global__ __launch_bounds__(256) void k_bn(const float* __restrict__ dpart,
                                            const float* __restrict__ gamma,
                                            const float* __restrict__ beta,
                                            float* __restrict__ bna,
                                            float* __restrict__ bnb) {
  const int c = blockIdx.x;
  const int tid = threadIdx.x;
  float s = 0.f, q = 0.f;
#pragma unroll
  for (int u = tid; u < 2048; u += 256) {
    int b = u >> 8, cb = u & 255;
    const float* part = dpart + ((size_t)(b * 256 + 192)) * 8192 + (size_t)cb * 512;
    s += part[c];
    q += part[256 + c];
  }
#pragma unroll
  for (int m = 1; m < 64; m <<= 1) {
    s += __shfl_xor(s, m);
    q += __shfl_xor(q, m);
  }
  __shared__ float ls[4], lq[4];
  if ((tid & 63) == 0) { ls[tid >> 6] = s; lq[tid >> 6] = q; }
  __syncthreads();
  if (tid == 0) {
    float st = ls[0] + ls[1] + ls[2] + ls[3];
    float qt = lq[0] + lq[1] + lq[2] + lq[3];
    const float invn = 1.0f / (float)(B * N);
    float mean = st * invn;
    float var = qt * invn - mean * mean;  // biased, matches reference
    float a = gamma[c] * rsqrtf(var + 1e-5f);
    bna[c] = a;
    bnb[c] = beta[c] - mean * a;
  }
}

// ------- k_fused1: out = relu(W1 @ relu(a*h+b) + b1), fp32 over all of d_out.
__global__ __launch_bounds__(256) void k_fused1(const uint32_t* h2,
                                                const _Float16* __restrict__ W1h,
                                                const float* __restrict__ b1,
                                                const float* __restrict__ bna,
                                                const float* __restrict__ bnb,
                                                float* out) {
  __shared__ uint32_t Hh[32 * 33 * 4];  // [kc][col(+1 pad)][k&7] halfs, 16.9 KB
  __shared__ float sa[256], sb[256], sb1[256];
  const int tid = threadIdx.x;
  const int b = blockIdx.x >> 8;
  const int n0 = (blockIdx.x & 255) * 32;
  sa[tid] = bna[tid]; sb[tid] = bnb[tid]; sb1[tid] = b1[tid];
  __syncthreads();
  {
    // 128 packed rows x 32 cols; each thread: 4 x uint4 (4 cols x 4 cps)
    const int c4 = tid & 7;          // col group: cols c4*4 .. c4*4+3
    const int rg = tid >> 3;         // 0..31
#pragma unroll
    for (int q = 0; q < 4; ++q) {
      const int cp = rg + 32 * q;    // 0..127
      const uint4 v = *(const uint4*)&h2[((size_t)(b * 256 + cp)) * 8192 + n0 + c4 * 4];
      const int k0 = 2 * cp;
      const float a0 = sa[k0], a1 = sa[k0 + 1], b0v = sb[k0], b1v = sb[k0 + 1];
      const int kc = cp >> 2, sub = cp & 3;
      const uint32_t vv[4] = {v.x, v.y, v.z, v.w};
#pragma unroll
      for (int m = 0; m < 4; ++m) {
        HU u; u.u = vv[m];
        float v0 = a0 * (float)u.h[0] + b0v;
        float v1 = a1 * (float)u.h[1] + b1v;
        HU o;
        o.h[0] = (_Float16)(v0 > 0.f ? v0 : 0.f);
        o.h[1] = (_Float16)(v1 > 0.f ? v1 : 0.f);
        Hh[((kc * 33) + c4 * 4 + m) * 4 + sub] = o.u;
      }
    }
  }
  __syncthreads();
  f32x4 acc[4][2] = {};
  const int wv = tid >> 6, lane = tid & 63;
  const int ln = lane & 15, quad = lane >> 4;
  for (int kk = 0; kk < 256; kk += 32) {
    half8 af[4], bf[2];
#pragma unroll
    for (int i = 0; i < 4; ++i) {
      int row = wv * 64 + i * 16 + ln;
      af[i] = *(const half8*)(W1h + (size_t)row * CMID + kk + quad * 8);
    }
#pragma unroll
    for (int j = 0; j < 2; ++j)
      bf[j] = *(const half8*)&Hh[(((kk >> 3) + quad) * 33 + j * 16 + ln) * 4];
#pragma unroll
    for (int i = 0; i < 4; ++i)
#pragma unroll
      for (int j = 0; j < 2; ++j)
        acc[i][j] = __builtin_amdgcn_mfma_f32_16x16x32_f16(af[i], bf[j], acc[i][j], 0, 0, 0);
  }
#pragma unroll
  for (int i = 0; i < 4; ++i) {
    const int rb = wv * 64 + i * 16 + quad * 4;
#pragma unroll
    for (int reg = 0; reg < 4; ++reg) {
      int row = rb + reg;
      float bias = sb1[row];
      float* orow = out + ((size_t)(b * 256 + row)) * 8192 + n0;
#pragma unroll
      for (int j = 0; j < 2; ++j)
        orow[j * 16 + ln] = fmaxf(acc[i][j][reg] + bias, 0.f);
    }
  }
}

extern "C" void kernel_launch(void* const* d_in, const int* in_sizes, int n_in,
                              void* d_out, int out_size, void* d_ws, size_t ws_size,
                              hipStream_t stream) {
  const float* xyz1 = (const float*)d_in[0];
  const float* xyz2 = (const float*)d_in[1];
  const float* points1 = (const float*)d_in[2];
  const float* points2 = (const float*)d_in[3];
  const float* W0 = (const float*)d_in[4];
  const float* b0 = (const float*)d_in[5];
  const float* gamma0 = (const float*)d_in[6];
  const float* beta0 = (const float*)d_in[7];
  const float* W1 = (const float*)d_in[8];
  const float* b1 = (const float*)d_in[9];
  float* out = (float*)d_out;

  // ws layout (788,480 B == R1's proven-safe size; do NOT grow):
  //   [0,1K) bna | [1K,2K) bnb | [2K..) W1h (128 KB) + W0h (64 KB)
  char* ws = (char*)d_ws;
  float* bna = (float*)ws;
  float* bnb = (float*)(ws + 1024);
  _Float16* W1h = (_Float16*)(ws + 2048);
  _Float16* W0h = (_Float16*)(ws + 2048 + 131072);
  // W0G lives in d_out rows 240..243 of b=0 (dead until k_fused1's final
  // overwrite; k_G consumes it before anything else touches that region).
  _Float16* W0G = (_Float16*)(out + (size_t)240 * 8192);

  k_wpack<<<dim3(160), 256, 0, stream>>>(W0, W1, W1h, W0h, W0G);
  k_top3a<<<dim3(N / 64, B, 4), 256, 0, stream>>>(xyz1, xyz2, out);
  k_G<<<dim3(B * 64), 256, 0, stream>>>(points2, W0G, out);
  k_interp<<<dim3(B * N / 32), 256, 0, stream>>>(xyz1, out, (uint32_t*)out);
  k_h<<<dim3(B * N / 32), 256, 0, stream>>>((uint32_t*)out, out, points1, W0h, b0);
  k_bn<<<dim3(256), 256, 0, stream>>>(out, gamma0, beta0, bna, bnb);
  k_fused1<<<dim3(B * N / 32), 256, 0, stream>>>((const uint32_t*)out, W1h, b1,
                                                 bna, bnb, out);
}